// Round 1
// baseline (39.109 us; speedup 1.0000x reference)
//
#include <hip/hip_runtime.h>
#include <math.h>

// Problem constants (fixed by setup_inputs)
#define B 64
#define T 60
#define NA 3
#define NS 3
#define BT (B*T)
#define NB_MAIN 2048
#define NB_CORR ((BT + 255) / 256)   // 15
#define N_TOTAL 6451200.0f           // 64*3*(160^2+80^2+40^2)

__device__ __forceinline__ float softplus_f(float x) {
    // stable: max(x,0) + log1p(exp(-|x|)) == jax.nn.softplus
    return fmaxf(x, 0.0f) + log1pf(expf(-fabsf(x)));
}

__device__ __forceinline__ float block_reduce_sum(float v) {
    // 256 threads = 4 waves of 64
    for (int o = 32; o > 0; o >>= 1) v += __shfl_down(v, o, 64);
    __shared__ float s[4];
    int lane = threadIdx.x & 63;
    int w = threadIdx.x >> 6;
    if (lane == 0) s[w] = v;
    __syncthreads();
    if (threadIdx.x == 0) {
        float t = 0.0f;
        #pragma unroll
        for (int i = 0; i < 4; ++i) t += s[i];
        return t;
    }
    return 0.0f;
}

// ---------------------------------------------------------------------------
// Kernel 1: sum softplus(x) over channel 4 of all three det tensors.
// Each "group" = 20 consecutive floats = 4 anchor-cells; logits at local
// float offsets 4,9,14,19 -> float4 lanes f1.x, f2.y, f3.z, f4.w.
// ---------------------------------------------------------------------------
__global__ void __launch_bounds__(256) main_sum_kernel(
    const float* __restrict__ d0, const float* __restrict__ d1,
    const float* __restrict__ d2, float* __restrict__ partials) {
    const int G0 = 24576000 / 20;  // 1228800
    const int G1 = 6144000 / 20;   // 307200
    const int G2 = 1536000 / 20;   // 76800
    const int G = G0 + G1 + G2;

    float acc = 0.0f;
    for (int g = blockIdx.x * blockDim.x + threadIdx.x; g < G;
         g += gridDim.x * blockDim.x) {
        const float4* p;
        int lg;
        if (g < G0)            { p = (const float4*)d0; lg = g; }
        else if (g < G0 + G1)  { p = (const float4*)d1; lg = g - G0; }
        else                   { p = (const float4*)d2; lg = g - G0 - G1; }
        int base = lg * 5;
        float4 f1 = p[base + 1];
        float4 f2 = p[base + 2];
        float4 f3 = p[base + 3];
        float4 f4 = p[base + 4];
        acc += softplus_f(f1.x) + softplus_f(f2.y) +
               softplus_f(f3.z) + softplus_f(f4.w);
    }
    float bs = block_reduce_sum(acc);
    if (threadIdx.x == 0) partials[blockIdx.x] = bs;
}

// ---------------------------------------------------------------------------
// Kernel 2: per-target sparse correction.
//   y in {1, -1, 0} from the reference's _suppress(_calc_overlap(...));
//   delta = f(x,y) - f(x,0) = -y*x - 0.5*y*softplus(-x)
// ---------------------------------------------------------------------------
__global__ void __launch_bounds__(256) corr_kernel(
    const float* __restrict__ d0, const float* __restrict__ d1,
    const float* __restrict__ d2, const float* __restrict__ anchors,
    const float* __restrict__ targets, float* __restrict__ corr_partials) {
    int tid = blockIdx.x * blockDim.x + threadIdx.x;
    float acc = 0.0f;
    if (tid < BT) {
        int bi = tid / T;
        const float* tg = targets + tid * 4;
        float tx = tg[0], ty = tg[1], tw = tg[2], th = tg[3];
        bool mask = (tx != -1.0f) && (ty != -1.0f) &&
                    (tw != -1.0f) && (th != -1.0f);
        const int dims[NS] = {160, 80, 40};
        const float* dets[NS] = {d0, d1, d2};

        float ov[NS][NA];
        float mx = -INFINITY;
        #pragma unroll
        for (int si = 0; si < NS; ++si) {
            float D = (float)dims[si];     // H == W at every scale
            float ztx = tx * D, zty = ty * D, ztw = tw * D, zth = th * D;
            float fx = ztx - (floorf(ztx) + 0.5f);
            float fy = zty - (floorf(zty) + 0.5f);
            float tarea = (ztw - fx) * (zth - fy);  // reference's exact expr
            #pragma unroll
            for (int ai = 0; ai < NA; ++ai) {
                float a0 = anchors[(si * NA + ai) * 2 + 0];
                float a1 = anchors[(si * NA + ai) * 2 + 1];
                float lb0 = fmaxf(-0.5f * a0, fx - 0.5f * ztw);
                float ub0 = fminf( 0.5f * a0, fx + 0.5f * ztw);
                float lb1 = fmaxf(-0.5f * a1, fy - 0.5f * zth);
                float ub1 = fminf( 0.5f * a1, fy + 0.5f * zth);
                float m = ((lb0 < ub0) && (lb1 < ub1)) ? 1.0f : 0.0f;
                float inter = (ub0 - lb0) * (ub1 - lb1) * m;
                float v = inter / (a0 * a1 + tarea - inter);
                ov[si][ai] = v;
                mx = fmaxf(mx, v);
            }
        }
        if (mask) {
            #pragma unroll
            for (int si = 0; si < NS; ++si) {
                int D = dims[si];
                int cy = (int)(ty * (float)D);
                int cx = (int)(tx * (float)D);
                if (cy < 0 || cy >= D || cx < 0 || cx >= D) continue;
                #pragma unroll
                for (int ai = 0; ai < NA; ++ai) {
                    float v = ov[si][ai];
                    float y = (v == mx) ? 1.0f : ((v < 0.5f) ? 0.0f : -1.0f);
                    if (y != 0.0f) {
                        long idx = ((((long)bi * NA + ai) * D + cy) * D + cx) * 5 + 4;
                        float x = dets[si][idx];
                        acc += -y * x - 0.5f * y * softplus_f(-x);
                    }
                }
            }
        }
    }
    float bs = block_reduce_sum(acc);
    if (threadIdx.x == 0) corr_partials[blockIdx.x] = bs;
}

// ---------------------------------------------------------------------------
// Kernel 3: deterministic final reduce of all partials -> mean.
// ---------------------------------------------------------------------------
__global__ void __launch_bounds__(256) final_kernel(
    const float* __restrict__ wsf, float* __restrict__ out) {
    float acc = 0.0f;
    for (int i = threadIdx.x; i < NB_MAIN + NB_CORR; i += blockDim.x)
        acc += wsf[i];
    float bs = block_reduce_sum(acc);
    if (threadIdx.x == 0) out[0] = bs / N_TOTAL;
}

extern "C" void kernel_launch(void* const* d_in, const int* in_sizes, int n_in,
                              void* d_out, int out_size, void* d_ws, size_t ws_size,
                              hipStream_t stream) {
    const float* det0    = (const float*)d_in[0];
    const float* det1    = (const float*)d_in[1];
    const float* det2    = (const float*)d_in[2];
    const float* anchors = (const float*)d_in[3];
    const float* targets = (const float*)d_in[4];
    float* out = (float*)d_out;
    float* wsf = (float*)d_ws;                 // [0,2048): main, [2048,2063): corr

    main_sum_kernel<<<NB_MAIN, 256, 0, stream>>>(det0, det1, det2, wsf);
    corr_kernel<<<NB_CORR, 256, 0, stream>>>(det0, det1, det2, anchors, targets,
                                             wsf + NB_MAIN);
    final_kernel<<<1, 256, 0, stream>>>(wsf, out);
}

// Round 2
// 32.332 us; speedup vs baseline: 1.2096x; 1.2096x over previous
//
#include <hip/hip_runtime.h>
#include <math.h>

// Problem constants (fixed by setup_inputs)
#define B 64
#define T 60
#define NA 3
#define NS 3
#define BT (B*T)
#define NB_MAIN 2048
#define NTHREADS (NB_MAIN * 256)     // 524288; NTHREADS % 5 == 3
#define N_TOTAL 6451200.0f           // 64*3*(160^2+80^2+40^2)

// float4 counts per det tensor
#define G4_0 6144000                 // 64*3*160*160*5/4
#define G4_1 1536000
#define G4_2 384000

__device__ __forceinline__ float softplus_f(float x) {
    // stable softplus with fast hw transcendentals; abs err < 1e-6
    float e = __expf(-fabsf(x));
    return fmaxf(x, 0.0f) + __logf(1.0f + e);
}

__device__ __forceinline__ float block_reduce_sum(float v) {
    // 256 threads = 4 waves of 64
    for (int o = 32; o > 0; o >>= 1) v += __shfl_down(v, o, 64);
    __shared__ float s[4];
    int lane = threadIdx.x & 63;
    int w = threadIdx.x >> 6;
    if (lane == 0) s[w] = v;
    __syncthreads();
    if (threadIdx.x == 0) {
        float t = 0.0f;
        #pragma unroll
        for (int i = 0; i < 4; ++i) t += s[i];
        return t;
    }
    return 0.0f;
}

// Linear, fully-coalesced scan of one det tensor: one float4 per lane per
// iteration. Logit lives at float index ≡ 4 (mod 5): within the 5-float4
// period, phase 0 has no logit, phase p∈{1..4} has it at component p-1.
__device__ __forceinline__ float scan_tensor(const float4* __restrict__ p,
                                             int n4, int tid) {
    float acc = 0.0f;
    int phase = tid % 5;
    for (int i = tid; i < n4; i += NTHREADS) {
        float4 f = p[i];
        float v = (phase == 1) ? f.x : (phase == 2) ? f.y
                : (phase == 3) ? f.z : f.w;
        if (phase != 0) acc += softplus_f(v);
        phase += 3;                  // NTHREADS % 5 == 3
        if (phase >= 5) phase -= 5;
    }
    return acc;
}

// ---------------------------------------------------------------------------
// Fused kernel: streaming softplus sum over all logits + sparse correction.
//   y in {1,-1,0}; delta = f(x,y) - f(x,0) = -y*x - 0.5*y*softplus(-x)
// ---------------------------------------------------------------------------
__global__ void __launch_bounds__(256) fused_main_kernel(
    const float* __restrict__ d0, const float* __restrict__ d1,
    const float* __restrict__ d2, const float* __restrict__ anchors,
    const float* __restrict__ targets, float* __restrict__ partials) {
    int tid = blockIdx.x * 256 + threadIdx.x;

    float acc = scan_tensor((const float4*)d0, G4_0, tid)
              + scan_tensor((const float4*)d1, G4_1, tid)
              + scan_tensor((const float4*)d2, G4_2, tid);

    if (tid < BT) {
        int bi = tid / T;
        const float* tg = targets + tid * 4;
        float tx = tg[0], ty = tg[1], tw = tg[2], th = tg[3];
        bool mask = (tx != -1.0f) && (ty != -1.0f) &&
                    (tw != -1.0f) && (th != -1.0f);
        const int dims[NS] = {160, 80, 40};
        const float* dets[NS] = {d0, d1, d2};

        float ov[NS][NA];
        float mx = -INFINITY;
        #pragma unroll
        for (int si = 0; si < NS; ++si) {
            float D = (float)dims[si];     // H == W at every scale
            float ztx = tx * D, zty = ty * D, ztw = tw * D, zth = th * D;
            float fx = ztx - (floorf(ztx) + 0.5f);
            float fy = zty - (floorf(zty) + 0.5f);
            float tarea = (ztw - fx) * (zth - fy);  // reference's exact expr
            #pragma unroll
            for (int ai = 0; ai < NA; ++ai) {
                float a0 = anchors[(si * NA + ai) * 2 + 0];
                float a1 = anchors[(si * NA + ai) * 2 + 1];
                float lb0 = fmaxf(-0.5f * a0, fx - 0.5f * ztw);
                float ub0 = fminf( 0.5f * a0, fx + 0.5f * ztw);
                float lb1 = fmaxf(-0.5f * a1, fy - 0.5f * zth);
                float ub1 = fminf( 0.5f * a1, fy + 0.5f * zth);
                float m = ((lb0 < ub0) && (lb1 < ub1)) ? 1.0f : 0.0f;
                float inter = (ub0 - lb0) * (ub1 - lb1) * m;
                float v = inter / (a0 * a1 + tarea - inter);
                ov[si][ai] = v;
                mx = fmaxf(mx, v);
            }
        }
        if (mask) {
            #pragma unroll
            for (int si = 0; si < NS; ++si) {
                int D = dims[si];
                int cy = (int)(ty * (float)D);
                int cx = (int)(tx * (float)D);
                if (cy >= 0 && cy < D && cx >= 0 && cx < D) {
                    #pragma unroll
                    for (int ai = 0; ai < NA; ++ai) {
                        float v = ov[si][ai];
                        float y = (v == mx) ? 1.0f
                                : ((v < 0.5f) ? 0.0f : -1.0f);
                        if (y != 0.0f) {
                            long idx = ((((long)bi * NA + ai) * D + cy) * D + cx) * 5 + 4;
                            float x = dets[si][idx];
                            acc += -y * x - 0.5f * y * softplus_f(-x);
                        }
                    }
                }
            }
        }
    }

    float bs = block_reduce_sum(acc);
    if (threadIdx.x == 0) partials[blockIdx.x] = bs;
}

// ---------------------------------------------------------------------------
// Final deterministic reduce of the 2048 block partials -> mean.
// ---------------------------------------------------------------------------
__global__ void __launch_bounds__(256) final_kernel(
    const float* __restrict__ wsf, float* __restrict__ out) {
    float acc = 0.0f;
    for (int i = threadIdx.x; i < NB_MAIN; i += blockDim.x)
        acc += wsf[i];
    float bs = block_reduce_sum(acc);
    if (threadIdx.x == 0) out[0] = bs / N_TOTAL;
}

extern "C" void kernel_launch(void* const* d_in, const int* in_sizes, int n_in,
                              void* d_out, int out_size, void* d_ws, size_t ws_size,
                              hipStream_t stream) {
    const float* det0    = (const float*)d_in[0];
    const float* det1    = (const float*)d_in[1];
    const float* det2    = (const float*)d_in[2];
    const float* anchors = (const float*)d_in[3];
    const float* targets = (const float*)d_in[4];
    float* out = (float*)d_out;
    float* wsf = (float*)d_ws;

    fused_main_kernel<<<NB_MAIN, 256, 0, stream>>>(det0, det1, det2,
                                                   anchors, targets, wsf);
    final_kernel<<<1, 256, 0, stream>>>(wsf, out);
}

// Round 3
// 30.617 us; speedup vs baseline: 1.2774x; 1.0560x over previous
//
#include <hip/hip_runtime.h>
#include <math.h>

// Problem constants (fixed by setup_inputs)
#define B 64
#define T 60
#define NA 3
#define NS 3
#define BT (B*T)
#define NB_SCAN 2048
#define NB_CORR ((BT + 255) / 256)    // 15
#define NB_ALL (NB_SCAN + NB_CORR)    // 2063
#define NTHREADS (NB_SCAN * 256)      // 524288; NTHREADS % 5 == 3
#define N_TOTAL 6451200.0f            // 64*3*(160^2+80^2+40^2)

// float4 counts per det tensor
#define G4_0 6144000                  // 64*3*160*160*5/4
#define G4_1 1536000
#define G4_2 384000

__device__ __forceinline__ float softplus_f(float x) {
    // stable softplus with fast hw transcendentals; abs err < 1e-6
    float e = __expf(-fabsf(x));
    return fmaxf(x, 0.0f) + __logf(1.0f + e);
}

__device__ __forceinline__ float pick(float4 f, int ph) {
    // ph in 1..4 -> component ph-1 (caller gates ph==0)
    return (ph == 1) ? f.x : (ph == 2) ? f.y : (ph == 3) ? f.z : f.w;
}

__device__ __forceinline__ float block_reduce_sum(float v) {
    for (int o = 32; o > 0; o >>= 1) v += __shfl_down(v, o, 64);
    __shared__ float s[4];
    int lane = threadIdx.x & 63;
    int w = threadIdx.x >> 6;
    if (lane == 0) s[w] = v;
    __syncthreads();
    if (threadIdx.x == 0) {
        float t = 0.0f;
        #pragma unroll
        for (int i = 0; i < 4; ++i) t += s[i];
        return t;
    }
    return 0.0f;
}

// Linear fully-coalesced scan; 4 grid-stride loads batched per macro-iter
// so 4 x 1KB wave-loads are outstanding before the first waitcnt.
// Logit = float index ≡ 4 (mod 5): float4 phase p∈{1..4} -> component p-1.
__device__ __forceinline__ float scan_tensor(const float4* __restrict__ p,
                                             int n4, int tid) {
    float acc = 0.0f;
    int i = tid;
    int phase = tid % 5;              // stride NTHREADS ≡ 3 (mod 5)
    while (i + 3 * NTHREADS < n4) {
        float4 f0 = p[i];
        float4 f1 = p[i + NTHREADS];
        float4 f2 = p[i + 2 * NTHREADS];
        float4 f3 = p[i + 3 * NTHREADS];
        int p0 = phase;
        int p1 = p0 + 3; if (p1 >= 5) p1 -= 5;
        int p2 = p1 + 3; if (p2 >= 5) p2 -= 5;
        int p3 = p2 + 3; if (p3 >= 5) p3 -= 5;
        if (p0) acc += softplus_f(pick(f0, p0));
        if (p1) acc += softplus_f(pick(f1, p1));
        if (p2) acc += softplus_f(pick(f2, p2));
        if (p3) acc += softplus_f(pick(f3, p3));
        phase = p3 + 3; if (phase >= 5) phase -= 5;
        i += 4 * NTHREADS;
    }
    for (; i < n4; i += NTHREADS) {
        float4 f = p[i];
        if (phase) acc += softplus_f(pick(f, phase));
        phase += 3; if (phase >= 5) phase -= 5;
    }
    return acc;
}

// ---------------------------------------------------------------------------
// One kernel, two block roles:
//   blockIdx <  2048: streaming softplus sum (register-lean path)
//   blockIdx >= 2048: sparse correction, delta = -y*x - 0.5*y*softplus(-x)
// __launch_bounds__(256,8) pins VGPR<=64 so the scan path keeps 32 waves/CU.
// ---------------------------------------------------------------------------
__global__ void __launch_bounds__(256, 8) fused_main_kernel(
    const float* __restrict__ d0, const float* __restrict__ d1,
    const float* __restrict__ d2, const float* __restrict__ anchors,
    const float* __restrict__ targets, float* __restrict__ partials) {
    float acc = 0.0f;

    if (blockIdx.x < NB_SCAN) {
        int tid = blockIdx.x * 256 + threadIdx.x;
        acc = scan_tensor((const float4*)d0, G4_0, tid)
            + scan_tensor((const float4*)d1, G4_1, tid)
            + scan_tensor((const float4*)d2, G4_2, tid);
    } else {
        int tid = (blockIdx.x - NB_SCAN) * 256 + threadIdx.x;
        if (tid < BT) {
            int bi = tid / T;
            const float* tg = targets + tid * 4;
            float tx = tg[0], ty = tg[1], tw = tg[2], th = tg[3];
            bool mask = (tx != -1.0f) && (ty != -1.0f) &&
                        (tw != -1.0f) && (th != -1.0f);
            const int dims[NS] = {160, 80, 40};
            const float* dets[NS] = {d0, d1, d2};

            float ov[NS][NA];
            float mx = -INFINITY;
            #pragma unroll
            for (int si = 0; si < NS; ++si) {
                float D = (float)dims[si];     // H == W at every scale
                float ztx = tx * D, zty = ty * D, ztw = tw * D, zth = th * D;
                float fx = ztx - (floorf(ztx) + 0.5f);
                float fy = zty - (floorf(zty) + 0.5f);
                float tarea = (ztw - fx) * (zth - fy);  // reference's exact expr
                #pragma unroll
                for (int ai = 0; ai < NA; ++ai) {
                    float a0 = anchors[(si * NA + ai) * 2 + 0];
                    float a1 = anchors[(si * NA + ai) * 2 + 1];
                    float lb0 = fmaxf(-0.5f * a0, fx - 0.5f * ztw);
                    float ub0 = fminf( 0.5f * a0, fx + 0.5f * ztw);
                    float lb1 = fmaxf(-0.5f * a1, fy - 0.5f * zth);
                    float ub1 = fminf( 0.5f * a1, fy + 0.5f * zth);
                    float m = ((lb0 < ub0) && (lb1 < ub1)) ? 1.0f : 0.0f;
                    float inter = (ub0 - lb0) * (ub1 - lb1) * m;
                    float v = inter / (a0 * a1 + tarea - inter);
                    ov[si][ai] = v;
                    mx = fmaxf(mx, v);
                }
            }
            if (mask) {
                #pragma unroll
                for (int si = 0; si < NS; ++si) {
                    int D = dims[si];
                    int cy = (int)(ty * (float)D);
                    int cx = (int)(tx * (float)D);
                    if (cy >= 0 && cy < D && cx >= 0 && cx < D) {
                        #pragma unroll
                        for (int ai = 0; ai < NA; ++ai) {
                            float v = ov[si][ai];
                            float y = (v == mx) ? 1.0f
                                    : ((v < 0.5f) ? 0.0f : -1.0f);
                            if (y != 0.0f) {
                                long idx = ((((long)bi * NA + ai) * D + cy) * D + cx) * 5 + 4;
                                float x = dets[si][idx];
                                acc += -y * x - 0.5f * y * softplus_f(-x);
                            }
                        }
                    }
                }
            }
        }
    }

    float bs = block_reduce_sum(acc);
    if (threadIdx.x == 0) partials[blockIdx.x] = bs;
}

// ---------------------------------------------------------------------------
// Final deterministic reduce of all 2063 block partials -> mean.
// ---------------------------------------------------------------------------
__global__ void __launch_bounds__(256) final_kernel(
    const float* __restrict__ wsf, float* __restrict__ out) {
    float acc = 0.0f;
    for (int i = threadIdx.x; i < NB_ALL; i += blockDim.x)
        acc += wsf[i];
    float bs = block_reduce_sum(acc);
    if (threadIdx.x == 0) out[0] = bs / N_TOTAL;
}

extern "C" void kernel_launch(void* const* d_in, const int* in_sizes, int n_in,
                              void* d_out, int out_size, void* d_ws, size_t ws_size,
                              hipStream_t stream) {
    const float* det0    = (const float*)d_in[0];
    const float* det1    = (const float*)d_in[1];
    const float* det2    = (const float*)d_in[2];
    const float* anchors = (const float*)d_in[3];
    const float* targets = (const float*)d_in[4];
    float* out = (float*)d_out;
    float* wsf = (float*)d_ws;

    fused_main_kernel<<<NB_ALL, 256, 0, stream>>>(det0, det1, det2,
                                                  anchors, targets, wsf);
    final_kernel<<<1, 256, 0, stream>>>(wsf, out);
}